// Round 8
// baseline (296.413 us; speedup 1.0000x reference)
//
#include <hip/hip_runtime.h>

#define FF_N 4096
#define S64  0.015625f   // 1/64 per FWHT (total 1/4096)

// In-register 16-point unnormalized WHT (static indexing -> VGPRs only).
__device__ __forceinline__ void h16(float v[16]) {
#pragma unroll
    for (int b = 1; b < 16; b <<= 1) {
#pragma unroll
        for (int r = 0; r < 16; ++r) {
            if ((r & b) == 0) {
                const float u = v[r];
                const float w = v[r | b];
                v[r]     = u + w;
                v[r | b] = u - w;
            }
        }
    }
}

// One row per 256-thread block, 16 f32/thread, radix-16 digit rotation.
// LDS: one 4096-dword (16 KB) buffer, reused by 5 junctions under two
// bijective XOR swizzles (conflict-free under rigid lane-group model):
//  Layout A (W1/W3/W4): dword = 4*(u ^ gA(u)) + (e&3), u = e>>2,
//     gA(u) = ((u>>3)&3) ^ ((u>>6)&3) ^ (((u>>6)&1)<<2)
//     -> f4 writes: 8 distinct bank-quads per 8-lane group (free)
//     -> stride-16 reads: exactly 2 lanes/bank (free)
//       addr(T,c,j) = 256T + 32*(j>>1) + 16*((j&1)^(T&1))
//                     + 4*((c>>2)^((j>>1)&3)^(T&3)) + (c&3)   [32-term: R7 bug]
//  Layout B (W2/W5): pair = u ^ ((u>>4)&7), dword = 2*pair + (e&1)
//     -> b64 writes: 16 distinct bank-pairs per 16-lane group (free)
//     -> stride-256 reads: exactly 2 lanes/bank (free), affine base
__global__ __launch_bounds__(256) void fastfood_r16x_kernel(
    const float* __restrict__ x,
    const float* __restrict__ diag_s,
    const float* __restrict__ diag_g,
    const float* __restrict__ diag_b,
    const int*   __restrict__ perm,
    float* __restrict__ out)
{
    __shared__ __align__(16) float lds[FF_N];   // exactly 16 KB
    const int t = threadIdx.x;
    const int T = t >> 4, c = t & 15;
    const size_t row = blockIdx.x;
    const float* __restrict__ xr   = x   + row * (size_t)FF_N;
    float* __restrict__       outr = out + row * (size_t)FF_N;

    // ---- per-thread swizzle constants ----
    const int gAw = ((t >> 1) & 3) ^ ((t >> 4) & 3) ^ (((t >> 4) & 1) << 2);
    int wqA[4];                       // layout-A f4-write dword bases, q=0..3
#pragma unroll
    for (int q = 0; q < 4; ++q) wqA[q] = ((4 * t + q) ^ gAw) << 2;

    const int A0 = 256 * T + (c & 3);           // stride-16 read pieces
    int t16[2]; t16[0] = 16 * (T & 1); t16[1] = 16 * ((T & 1) ^ 1);
    const int mA = (c >> 2) ^ (T & 3);
    int m4[4];
#pragma unroll
    for (int q = 0; q < 4; ++q) m4[q] = 4 * (mA ^ q);

    const int hB = (t >> 1) & 7;                // layout-B write swizzle
    int wqB[8];                                 // b64-write dword bases, q'=0..7
#pragma unroll
    for (int q = 0; q < 8; ++q) wqB[q] = 16 * t + 2 * (q ^ hB);
    const int BRB = 2 * ((t >> 1) ^ ((t >> 5) & 7)) + (t & 1);  // stride-256 read base

    float v[16];

    // ===== P1: load x*diag_b (f4, coalesced); h16 over d0; W1 f4-writes (A) =====
    {
        const float4* __restrict__ x4 = (const float4*)(xr + 16 * t);
        const float4* __restrict__ b4 = (const float4*)(diag_b + 16 * t);
#pragma unroll
        for (int q = 0; q < 4; ++q) {
            const float4 xv = x4[q];
            const float4 bv = b4[q];
            v[4 * q + 0] = xv.x * bv.x;
            v[4 * q + 1] = xv.y * bv.y;
            v[4 * q + 2] = xv.z * bv.z;
            v[4 * q + 3] = xv.w * bv.w;
        }
        h16(v);
#pragma unroll
        for (int q = 0; q < 4; ++q)
            *(float4*)&lds[wqA[q]] =
                make_float4(v[4 * q], v[4 * q + 1], v[4 * q + 2], v[4 * q + 3]);
    }
    __syncthreads();

    // ===== P2: stride-16 read (A); h16 over d1; W2 b64-writes (B) =====
#pragma unroll
    for (int j = 0; j < 16; ++j)
        v[j] = lds[A0 + 32 * (j >> 1) + t16[j & 1] + m4[(j >> 1) & 3]];
    h16(v);
    __syncthreads();
#pragma unroll
    for (int q = 0; q < 8; ++q)
        *(float2*)&lds[wqB[q]] = make_float2(v[2 * q], v[2 * q + 1]);
    __syncthreads();

    // ===== P3: stride-256 read (B); h16 over d2 (FWHT1 done); W3 f4-writes (A) =====
#pragma unroll
    for (int j = 0; j < 16; ++j) v[j] = lds[BRB + 256 * j];
    h16(v);
    __syncthreads();
#pragma unroll
    for (int q = 0; q < 4; ++q)
        *(float4*)&lds[wqA[q]] =
            make_float4(v[4 * q], v[4 * q + 1], v[4 * q + 2], v[4 * q + 3]);
    __syncthreads();

    // ===== P4: perm gather (A) * diag_g/64; h16 over d0'; W4 f4-writes (A) =====
    {
        const int4*   __restrict__ p4 = (const int4*)(perm + 16 * t);
        const float4* __restrict__ g4 = (const float4*)(diag_g + 16 * t);
        int   p[16];
        float g[16];
#pragma unroll
        for (int q = 0; q < 4; ++q) {
            const int4   pv = p4[q];
            const float4 gv = g4[q];
            p[4 * q + 0] = pv.x; p[4 * q + 1] = pv.y;
            p[4 * q + 2] = pv.z; p[4 * q + 3] = pv.w;
            g[4 * q + 0] = gv.x; g[4 * q + 1] = gv.y;
            g[4 * q + 2] = gv.z; g[4 * q + 3] = gv.w;
        }
#pragma unroll
        for (int j = 0; j < 16; ++j) {
            const int pe = p[j];
            // W3 linear index of post-perm element pe: 256*d0 + 16*d1 + d2
            const int a  = ((pe & 15) << 8) + (pe & 240) + (pe >> 8);
            const int u  = a >> 2;
            const int gA = ((u >> 3) & 3) ^ ((u >> 6) & 3) ^ (((u >> 6) & 1) << 2);
            v[j] = lds[((u ^ gA) << 2) | (a & 3)] * (g[j] * S64);
        }
        h16(v);
    }
    __syncthreads();
#pragma unroll
    for (int q = 0; q < 4; ++q)
        *(float4*)&lds[wqA[q]] =
            make_float4(v[4 * q], v[4 * q + 1], v[4 * q + 2], v[4 * q + 3]);
    __syncthreads();

    // ===== P5: stride-16 read (A); h16 over d1'; W5 b64-writes (B) =====
#pragma unroll
    for (int j = 0; j < 16; ++j)
        v[j] = lds[A0 + 32 * (j >> 1) + t16[j & 1] + m4[(j >> 1) & 3]];
    h16(v);
    __syncthreads();
#pragma unroll
    for (int q = 0; q < 8; ++q)
        *(float2*)&lds[wqB[q]] = make_float2(v[2 * q], v[2 * q + 1]);
    __syncthreads();

    // ===== P6: stride-256 read (B); h16 over d2'; store *diag_s/64 =====
    // out element = 256*j + 16*c + T: each 64B line receives one contiguous
    // 16B chunk per wave; complementary chunks merge in L2 (R6: WRITE_SIZE
    // was exactly output-sized, no amplification).
#pragma unroll
    for (int j = 0; j < 16; ++j) v[j] = lds[BRB + 256 * j];
    h16(v);
    {
        const int ob = 16 * c + T;
#pragma unroll
        for (int j = 0; j < 16; ++j) {
            const int e = 256 * j + ob;
            outr[e] = v[j] * (diag_s[e] * S64);
        }
    }
}

extern "C" void kernel_launch(void* const* d_in, const int* in_sizes, int n_in,
                              void* d_out, int out_size, void* d_ws, size_t ws_size,
                              hipStream_t stream) {
    const float* x      = (const float*)d_in[0];
    const float* diag_s = (const float*)d_in[1];
    const float* diag_g = (const float*)d_in[2];
    const float* diag_b = (const float*)d_in[3];
    const int*   perm   = (const int*)d_in[4];
    float* out = (float*)d_out;

    const int batch = in_sizes[0] / FF_N;   // 16384 rows
    fastfood_r16x_kernel<<<batch, 256, 0, stream>>>(x, diag_s, diag_g, diag_b, perm, out);
}

// Round 9
// 143.010 us; speedup vs baseline: 2.0727x; 2.0727x over previous
//
#include <hip/hip_runtime.h>

#define FF_N 4096
#define S64  0.015625f   // 1/64 per FWHT (total 1/4096)

// In-register 16-point unnormalized WHT (static indexing -> VGPRs only).
__device__ __forceinline__ void h16(float v[16]) {
#pragma unroll
    for (int b = 1; b < 16; b <<= 1) {
#pragma unroll
        for (int r = 0; r < 16; ++r) {
            if ((r & b) == 0) {
                const float u = v[r];
                const float w = v[r | b];
                v[r]     = u + w;
                v[r | b] = u - w;
            }
        }
    }
}

// One row per 256-thread block, 16 f32/thread, radix-16 digit rotation.
// LDS: one 4096-dword (16 KB) buffer, reused by 5 junctions. All patterns
// conflict-free under the rigid lane-group model (validated R8: 38.7M->5.4M):
//  Layout A (W1/W3/W4, f4 writes + stride-16 reads): dword = 4*(u^gA(u)) + (e&3),
//     u = e>>2, gA(u) = ((u>>3)&3) ^ ((u>>6)&3) ^ (((u>>6)&1)<<2)
//  Layout P (W2/W5, b64 pair writes + stride-256 reads) — pure bit permutation:
//     dword = 256*d2 + 32*(d1>>1) + 2*d0 + (d1&1)
//     -> b64 writes (d1-adjacent pairs): 16 distinct bank-pairs per 16-lane
//        group (free); stride-256 reads: exactly 2 lanes/bank (free), affine.
//     P6 read delivers element 256j + t to lane t -> DENSE final store.
__global__ __launch_bounds__(256) void fastfood_r16d_kernel(
    const float* __restrict__ x,
    const float* __restrict__ diag_s,
    const float* __restrict__ diag_g,
    const float* __restrict__ diag_b,
    const int*   __restrict__ perm,
    float* __restrict__ out)
{
    __shared__ __align__(16) float lds[FF_N];   // exactly 16 KB
    const int t = threadIdx.x;
    const int T = t >> 4, c = t & 15;
    const size_t row = blockIdx.x;
    const float* __restrict__ xr   = x   + row * (size_t)FF_N;
    float* __restrict__       outr = out + row * (size_t)FF_N;

    // ---- per-thread constants ----
    const int gAw = ((t >> 1) & 3) ^ ((t >> 4) & 3) ^ (((t >> 4) & 1) << 2);
    int wqA[4];                       // layout-A f4-write dword bases, q=0..3
#pragma unroll
    for (int q = 0; q < 4; ++q) wqA[q] = ((4 * t + q) ^ gAw) << 2;

    const int A0 = 256 * T + (c & 3);           // layout-A stride-16 read pieces
    int t16[2]; t16[0] = 16 * (T & 1); t16[1] = 16 * ((T & 1) ^ 1);
    const int mA = (c >> 2) ^ (T & 3);
    int m4[4];
#pragma unroll
    for (int q = 0; q < 4; ++q) m4[q] = 4 * (mA ^ q);

    const int WPB = 256 * T + 2 * c;            // layout-P pair-write base (+32q)
    const int BRP = 32 * (T >> 1) + 2 * c + (T & 1);   // layout-P read base (+256j)

    float v[16];

    // ===== P1: load x*diag_b (f4, coalesced); h16 over d0; W1 f4-writes (A) =====
    {
        const float4* __restrict__ x4 = (const float4*)(xr + 16 * t);
        const float4* __restrict__ b4 = (const float4*)(diag_b + 16 * t);
#pragma unroll
        for (int q = 0; q < 4; ++q) {
            const float4 xv = x4[q];
            const float4 bv = b4[q];
            v[4 * q + 0] = xv.x * bv.x;
            v[4 * q + 1] = xv.y * bv.y;
            v[4 * q + 2] = xv.z * bv.z;
            v[4 * q + 3] = xv.w * bv.w;
        }
        h16(v);
#pragma unroll
        for (int q = 0; q < 4; ++q)
            *(float4*)&lds[wqA[q]] =
                make_float4(v[4 * q], v[4 * q + 1], v[4 * q + 2], v[4 * q + 3]);
    }
    __syncthreads();

    // ===== P2: stride-16 read (A); h16 over d1; W2 pair-writes (P) =====
#pragma unroll
    for (int j = 0; j < 16; ++j)
        v[j] = lds[A0 + 32 * (j >> 1) + t16[j & 1] + m4[(j >> 1) & 3]];
    h16(v);
    __syncthreads();
#pragma unroll
    for (int q = 0; q < 8; ++q)
        *(float2*)&lds[WPB + 32 * q] = make_float2(v[2 * q], v[2 * q + 1]);
    __syncthreads();

    // ===== P3: stride-256 read (P) -> lane t holds (d2=j, d1=T, d0=c);
    //       h16 over d2 (FWHT1 done); W3 f4-writes (A) at a' = 16t + j =====
#pragma unroll
    for (int j = 0; j < 16; ++j) v[j] = lds[BRP + 256 * j];
    h16(v);
    __syncthreads();
#pragma unroll
    for (int q = 0; q < 4; ++q)
        *(float4*)&lds[wqA[q]] =
            make_float4(v[4 * q], v[4 * q + 1], v[4 * q + 2], v[4 * q + 3]);
    __syncthreads();

    // ===== P4: perm gather (A) * diag_g/64; h16 over d0'; W4 f4-writes (A) =====
    // FWHT1 element pe = (d2,d1,d0) sits at pseudo-linear a = 256*d1+16*d0+d2
    //                  = ((pe & 255) << 4) + (pe >> 8), then swizzle A.
    {
        const int4*   __restrict__ p4 = (const int4*)(perm + 16 * t);
        const float4* __restrict__ g4 = (const float4*)(diag_g + 16 * t);
        int   p[16];
        float g[16];
#pragma unroll
        for (int q = 0; q < 4; ++q) {
            const int4   pv = p4[q];
            const float4 gv = g4[q];
            p[4 * q + 0] = pv.x; p[4 * q + 1] = pv.y;
            p[4 * q + 2] = pv.z; p[4 * q + 3] = pv.w;
            g[4 * q + 0] = gv.x; g[4 * q + 1] = gv.y;
            g[4 * q + 2] = gv.z; g[4 * q + 3] = gv.w;
        }
#pragma unroll
        for (int j = 0; j < 16; ++j) {
            const int pe = p[j];
            const int a  = ((pe & 255) << 4) + (pe >> 8);
            const int u  = a >> 2;
            const int gA = ((u >> 3) & 3) ^ ((u >> 6) & 3) ^ (((u >> 6) & 1) << 2);
            v[j] = lds[((u ^ gA) << 2) | (a & 3)] * (g[j] * S64);
        }
        h16(v);
    }
    __syncthreads();
#pragma unroll
    for (int q = 0; q < 4; ++q)
        *(float4*)&lds[wqA[q]] =
            make_float4(v[4 * q], v[4 * q + 1], v[4 * q + 2], v[4 * q + 3]);
    __syncthreads();

    // ===== P5: stride-16 read (A); h16 over d1'; W5 pair-writes (P) =====
#pragma unroll
    for (int j = 0; j < 16; ++j)
        v[j] = lds[A0 + 32 * (j >> 1) + t16[j & 1] + m4[(j >> 1) & 3]];
    h16(v);
    __syncthreads();
#pragma unroll
    for (int q = 0; q < 8; ++q)
        *(float2*)&lds[WPB + 32 * q] = make_float2(v[2 * q], v[2 * q + 1]);
    __syncthreads();

    // ===== P6: stride-256 read (P) -> lane t holds (d2'=j, d1'=T, d0'=c);
    //       h16 over d2'; DENSE store out[256j + t] * diag_s/64 =====
#pragma unroll
    for (int j = 0; j < 16; ++j) v[j] = lds[BRP + 256 * j];
    h16(v);
#pragma unroll
    for (int j = 0; j < 16; ++j) {
        const int e = 256 * j + t;
        outr[e] = v[j] * (diag_s[e] * S64);
    }
}

extern "C" void kernel_launch(void* const* d_in, const int* in_sizes, int n_in,
                              void* d_out, int out_size, void* d_ws, size_t ws_size,
                              hipStream_t stream) {
    const float* x      = (const float*)d_in[0];
    const float* diag_s = (const float*)d_in[1];
    const float* diag_g = (const float*)d_in[2];
    const float* diag_b = (const float*)d_in[3];
    const int*   perm   = (const int*)d_in[4];
    float* out = (float*)d_out;

    const int batch = in_sizes[0] / FF_N;   // 16384 rows
    fastfood_r16d_kernel<<<batch, 256, 0, stream>>>(x, diag_s, diag_g, diag_b, perm, out);
}

// Round 10
// 114.911 us; speedup vs baseline: 2.5795x; 1.2445x over previous
//
#include <hip/hip_runtime.h>

#define FF_N 4096
#define S64  0.015625f   // 1/64 per FWHT (total 1/4096)

// In-register 16-point unnormalized WHT (static indexing -> VGPRs only).
__device__ __forceinline__ void h16(float v[16]) {
#pragma unroll
    for (int b = 1; b < 16; b <<= 1) {
#pragma unroll
        for (int r = 0; r < 16; ++r) {
            if ((r & b) == 0) {
                const float u = v[r];
                const float w = v[r | b];
                v[r]     = u + w;
                v[r | b] = u - w;
            }
        }
    }
}

// Per-launch precompute (row-invariant data, ~3 us):
//  gaddr[k] = swizzled W3 LDS dword address of FWHT1-output element perm[k]
//             (exactly R9's P4 formula, hoisted out of all 16384 blocks)
//  gg[k] = diag_g[k]/64, ss[k] = diag_s[k]/64
__global__ void ff_setup(const float* __restrict__ diag_s,
                         const float* __restrict__ diag_g,
                         const int*   __restrict__ perm,
                         int*   __restrict__ gaddr,
                         float* __restrict__ gg,
                         float* __restrict__ ss) {
    const int k  = blockIdx.x * 256 + threadIdx.x;
    const int pe = perm[k];
    const int a  = ((pe & 255) << 4) + (pe >> 8);
    const int u  = a >> 2;
    const int gA = ((u >> 3) & 3) ^ ((u >> 6) & 3) ^ (((u >> 6) & 1) << 2);
    gaddr[k] = ((u ^ gA) << 2) | (a & 3);
    gg[k] = diag_g[k] * S64;
    ss[k] = diag_s[k] * S64;
}

// TWO rows per 256-thread block, phase-interleaved (issue A-reads, B-reads,
// then compute A while B completes). Layouts identical to R9 (conflict-
// verified: 5.3M residual = inherent gather only).
__global__ __launch_bounds__(256) void fastfood_r2x_kernel(
    const float* __restrict__ x,
    const float* __restrict__ diag_b,
    const int*   __restrict__ gaddr,
    const float* __restrict__ gg,
    const float* __restrict__ ss,
    float* __restrict__ out)
{
    __shared__ __align__(16) float ldsA[FF_N];
    __shared__ __align__(16) float ldsB[FF_N];
    const int t = threadIdx.x;
    const int T = t >> 4, c = t & 15;
    const size_t rowA = (size_t)blockIdx.x * 2;
    const float* __restrict__ xA   = x   + rowA * FF_N;
    const float* __restrict__ xB   = xA  + FF_N;
    float* __restrict__       outA = out + rowA * FF_N;
    float* __restrict__       outB = outA + FF_N;

    // ---- per-thread constants (R9 verbatim) ----
    const int gAw = ((t >> 1) & 3) ^ ((t >> 4) & 3) ^ (((t >> 4) & 1) << 2);
    int wqA[4];
#pragma unroll
    for (int q = 0; q < 4; ++q) wqA[q] = ((4 * t + q) ^ gAw) << 2;

    const int A0 = 256 * T + (c & 3);
    int t16[2]; t16[0] = 16 * (T & 1); t16[1] = 16 * ((T & 1) ^ 1);
    const int mA = (c >> 2) ^ (T & 3);
    int m4[4];
#pragma unroll
    for (int q = 0; q < 4; ++q) m4[q] = 4 * (mA ^ q);

    const int WPB = 256 * T + 2 * c;
    const int BRP = 32 * (T >> 1) + 2 * c + (T & 1);

    float vA[16], vB[16];

    // ===== P1: load x*diag_b both rows (diag_b shared); h16 d0; W1 (A-layout) =====
    {
        const float4* __restrict__ xa4 = (const float4*)(xA + 16 * t);
        const float4* __restrict__ xb4 = (const float4*)(xB + 16 * t);
        const float4* __restrict__ b4  = (const float4*)(diag_b + 16 * t);
#pragma unroll
        for (int q = 0; q < 4; ++q) {
            const float4 bv = b4[q];
            const float4 av = xa4[q];
            const float4 wv = xb4[q];
            vA[4 * q + 0] = av.x * bv.x;  vB[4 * q + 0] = wv.x * bv.x;
            vA[4 * q + 1] = av.y * bv.y;  vB[4 * q + 1] = wv.y * bv.y;
            vA[4 * q + 2] = av.z * bv.z;  vB[4 * q + 2] = wv.z * bv.z;
            vA[4 * q + 3] = av.w * bv.w;  vB[4 * q + 3] = wv.w * bv.w;
        }
        h16(vA); h16(vB);
#pragma unroll
        for (int q = 0; q < 4; ++q) {
            *(float4*)&ldsA[wqA[q]] =
                make_float4(vA[4 * q], vA[4 * q + 1], vA[4 * q + 2], vA[4 * q + 3]);
            *(float4*)&ldsB[wqA[q]] =
                make_float4(vB[4 * q], vB[4 * q + 1], vB[4 * q + 2], vB[4 * q + 3]);
        }
    }
    __syncthreads();

    // ===== P2: stride-16 reads (A-layout) both rows; h16 d1; W2 (P-layout) =====
#pragma unroll
    for (int j = 0; j < 16; ++j)
        vA[j] = ldsA[A0 + 32 * (j >> 1) + t16[j & 1] + m4[(j >> 1) & 3]];
#pragma unroll
    for (int j = 0; j < 16; ++j)
        vB[j] = ldsB[A0 + 32 * (j >> 1) + t16[j & 1] + m4[(j >> 1) & 3]];
    h16(vA); h16(vB);
    __syncthreads();
#pragma unroll
    for (int q = 0; q < 8; ++q) {
        *(float2*)&ldsA[WPB + 32 * q] = make_float2(vA[2 * q], vA[2 * q + 1]);
        *(float2*)&ldsB[WPB + 32 * q] = make_float2(vB[2 * q], vB[2 * q + 1]);
    }
    __syncthreads();

    // ===== P3: stride-256 reads (P-layout); h16 d2 (FWHT1 done); W3 (A-layout) =====
#pragma unroll
    for (int j = 0; j < 16; ++j) vA[j] = ldsA[BRP + 256 * j];
#pragma unroll
    for (int j = 0; j < 16; ++j) vB[j] = ldsB[BRP + 256 * j];
    h16(vA); h16(vB);
    __syncthreads();
#pragma unroll
    for (int q = 0; q < 4; ++q) {
        *(float4*)&ldsA[wqA[q]] =
            make_float4(vA[4 * q], vA[4 * q + 1], vA[4 * q + 2], vA[4 * q + 3]);
        *(float4*)&ldsB[wqA[q]] =
            make_float4(vB[4 * q], vB[4 * q + 1], vB[4 * q + 2], vB[4 * q + 3]);
    }
    __syncthreads();

    // ===== P4: precomputed gather, both rows; h16 d0'; W4 (A-layout) =====
    {
        const int4*   __restrict__ ga4 = (const int4*)(gaddr + 16 * t);
        const float4* __restrict__ gg4 = (const float4*)(gg + 16 * t);
#pragma unroll
        for (int q = 0; q < 4; ++q) {
            const int4   pa = ga4[q];
            const float4 gv = gg4[q];
            vA[4 * q + 0] = ldsA[pa.x] * gv.x;  vB[4 * q + 0] = ldsB[pa.x] * gv.x;
            vA[4 * q + 1] = ldsA[pa.y] * gv.y;  vB[4 * q + 1] = ldsB[pa.y] * gv.y;
            vA[4 * q + 2] = ldsA[pa.z] * gv.z;  vB[4 * q + 2] = ldsB[pa.z] * gv.z;
            vA[4 * q + 3] = ldsA[pa.w] * gv.w;  vB[4 * q + 3] = ldsB[pa.w] * gv.w;
        }
        h16(vA); h16(vB);
    }
    __syncthreads();
#pragma unroll
    for (int q = 0; q < 4; ++q) {
        *(float4*)&ldsA[wqA[q]] =
            make_float4(vA[4 * q], vA[4 * q + 1], vA[4 * q + 2], vA[4 * q + 3]);
        *(float4*)&ldsB[wqA[q]] =
            make_float4(vB[4 * q], vB[4 * q + 1], vB[4 * q + 2], vB[4 * q + 3]);
    }
    __syncthreads();

    // ===== P5: stride-16 reads (A-layout); h16 d1'; W5 (P-layout) =====
#pragma unroll
    for (int j = 0; j < 16; ++j)
        vA[j] = ldsA[A0 + 32 * (j >> 1) + t16[j & 1] + m4[(j >> 1) & 3]];
#pragma unroll
    for (int j = 0; j < 16; ++j)
        vB[j] = ldsB[A0 + 32 * (j >> 1) + t16[j & 1] + m4[(j >> 1) & 3]];
    h16(vA); h16(vB);
    __syncthreads();
#pragma unroll
    for (int q = 0; q < 8; ++q) {
        *(float2*)&ldsA[WPB + 32 * q] = make_float2(vA[2 * q], vA[2 * q + 1]);
        *(float2*)&ldsB[WPB + 32 * q] = make_float2(vB[2 * q], vB[2 * q + 1]);
    }
    __syncthreads();

    // ===== P6: stride-256 reads (P-layout); h16 d2'; DENSE stores * ss =====
#pragma unroll
    for (int j = 0; j < 16; ++j) vA[j] = ldsA[BRP + 256 * j];
#pragma unroll
    for (int j = 0; j < 16; ++j) vB[j] = ldsB[BRP + 256 * j];
    h16(vA); h16(vB);
#pragma unroll
    for (int j = 0; j < 16; ++j) {
        const int e = 256 * j + t;
        const float s = ss[e];
        outA[e] = vA[j] * s;
        outB[e] = vB[j] * s;
    }
}

extern "C" void kernel_launch(void* const* d_in, const int* in_sizes, int n_in,
                              void* d_out, int out_size, void* d_ws, size_t ws_size,
                              hipStream_t stream) {
    const float* x      = (const float*)d_in[0];
    const float* diag_s = (const float*)d_in[1];
    const float* diag_g = (const float*)d_in[2];
    const float* diag_b = (const float*)d_in[3];
    const int*   perm   = (const int*)d_in[4];
    float* out = (float*)d_out;

    int*   gaddr = (int*)d_ws;
    float* gg    = (float*)d_ws + FF_N;
    float* ss    = (float*)d_ws + 2 * FF_N;

    ff_setup<<<FF_N / 256, 256, 0, stream>>>(diag_s, diag_g, perm, gaddr, gg, ss);

    const int batch = in_sizes[0] / FF_N;   // 16384 rows
    fastfood_r2x_kernel<<<batch / 2, 256, 0, stream>>>(x, diag_b, gaddr, gg, ss, out);
}